// Round 1
// baseline (621.525 us; speedup 1.0000x reference)
//
#include <hip/hip_runtime.h>

#define NN 100000
#define NE 1600000
#define SCAN_B 1024

static inline size_t alignup(size_t x) { return (x + 255) & ~(size_t)255; }

// ---------------- graph prep ----------------

__global__ __launch_bounds__(256) void k_init(int* __restrict__ deg, int* __restrict__ cursor) {
  int i = blockIdx.x * 256 + threadIdx.x;
  if (i < NN) { deg[i] = 1; cursor[i] = 0; }  // deg starts at 1 (self loop)
}

__global__ __launch_bounds__(256) void k_count(const int* __restrict__ col, int* __restrict__ deg) {
  int e = blockIdx.x * 256 + threadIdx.x;
  if (e < NE) atomicAdd(&deg[col[e]], 1);
}

__global__ __launch_bounds__(256) void k_dinv(const int* __restrict__ deg, float* __restrict__ dinv) {
  int i = blockIdx.x * 256 + threadIdx.x;
  if (i < NN) dinv[i] = rsqrtf((float)deg[i]);
}

// exclusive scan of (deg-1) -> offs, 3-kernel standard scan
__global__ __launch_bounds__(SCAN_B) void k_scan1(const int* __restrict__ deg, int* __restrict__ offs,
                                                  int* __restrict__ bsums) {
  __shared__ int sm[SCAN_B];
  int i = blockIdx.x * SCAN_B + threadIdx.x;
  int v = (i < NN) ? (deg[i] - 1) : 0;
  sm[threadIdx.x] = v;
  __syncthreads();
  for (int d = 1; d < SCAN_B; d <<= 1) {
    int t = (threadIdx.x >= d) ? sm[threadIdx.x - d] : 0;
    __syncthreads();
    sm[threadIdx.x] += t;
    __syncthreads();
  }
  if (i < NN) offs[i] = sm[threadIdx.x] - v;
  if (threadIdx.x == SCAN_B - 1) bsums[blockIdx.x] = sm[threadIdx.x];
}

__global__ __launch_bounds__(128) void k_scan2(int* __restrict__ bsums, int nb) {
  __shared__ int sm[128];
  int v = (threadIdx.x < nb) ? bsums[threadIdx.x] : 0;
  sm[threadIdx.x] = v;
  __syncthreads();
  for (int d = 1; d < 128; d <<= 1) {
    int t = (threadIdx.x >= d) ? sm[threadIdx.x - d] : 0;
    __syncthreads();
    sm[threadIdx.x] += t;
    __syncthreads();
  }
  if (threadIdx.x < nb) bsums[threadIdx.x] = sm[threadIdx.x] - v;
}

__global__ __launch_bounds__(SCAN_B) void k_scan3(int* __restrict__ offs, const int* __restrict__ bsums) {
  int i = blockIdx.x * SCAN_B + threadIdx.x;
  if (i < NN) offs[i] += bsums[blockIdx.x];
}

__global__ __launch_bounds__(256) void k_fill(const int* __restrict__ row, const int* __restrict__ col,
                                              const int* __restrict__ offs, int* __restrict__ cursor,
                                              int* __restrict__ csr) {
  int e = blockIdx.x * 256 + threadIdx.x;
  if (e < NE) {
    int c = col[e];
    int p = atomicAdd(&cursor[c], 1);
    csr[offs[c] + p] = row[e];
  }
}

// ---------------- dense transforms (fp32 vector ALU, W in LDS) ----------------

// t[N,128] = x[N,128] @ W[128,128] ; 4 waves/block, 4 rows/wave, 2 cols/lane
__global__ __launch_bounds__(256) void k_gemm128(const float* __restrict__ x, const float* __restrict__ W,
                                                 float* __restrict__ out) {
  __shared__ float Ws[128 * 128];
  for (int i = threadIdx.x * 4; i < 128 * 128; i += 256 * 4)
    *(float4*)&Ws[i] = *(const float4*)&W[i];
  __syncthreads();
  int wave = threadIdx.x >> 6, lane = threadIdx.x & 63;
  int row0 = blockIdx.x * 16 + wave * 4;
  const float* xr = x + (size_t)row0 * 128;
  float acc[4][2] = {};
  for (int k = 0; k < 128; k += 4) {
    float4 xv[4];
#pragma unroll
    for (int r = 0; r < 4; r++) xv[r] = *(const float4*)&xr[r * 128 + k];
#pragma unroll
    for (int kk = 0; kk < 4; kk++) {
      float w0 = Ws[(k + kk) * 128 + lane];
      float w1 = Ws[(k + kk) * 128 + lane + 64];
#pragma unroll
      for (int r = 0; r < 4; r++) {
        float xs = (&xv[r].x)[kk];
        acc[r][0] = fmaf(xs, w0, acc[r][0]);
        acc[r][1] = fmaf(xs, w1, acc[r][1]);
      }
    }
  }
#pragma unroll
  for (int r = 0; r < 4; r++) {
    out[(size_t)(row0 + r) * 128 + lane] = acc[r][0];
    out[(size_t)(row0 + r) * 128 + lane + 64] = acc[r][1];
  }
}

// t[N,64] = h[N,128] @ W[128,64] ; 4 waves/block, 8 rows/wave, 1 col/lane
__global__ __launch_bounds__(256) void k_gemm64(const float* __restrict__ h, const float* __restrict__ W,
                                                float* __restrict__ out) {
  __shared__ float Ws[128 * 64];
  for (int i = threadIdx.x * 4; i < 128 * 64; i += 256 * 4)
    *(float4*)&Ws[i] = *(const float4*)&W[i];
  __syncthreads();
  int wave = threadIdx.x >> 6, lane = threadIdx.x & 63;
  int row0 = blockIdx.x * 32 + wave * 8;
  const float* hr = h + (size_t)row0 * 128;
  float acc[8] = {};
  for (int k = 0; k < 128; k += 4) {
    float4 xv[8];
#pragma unroll
    for (int r = 0; r < 8; r++) xv[r] = *(const float4*)&hr[r * 128 + k];
#pragma unroll
    for (int kk = 0; kk < 4; kk++) {
      float w0 = Ws[(k + kk) * 64 + lane];
#pragma unroll
      for (int r = 0; r < 8; r++) acc[r] = fmaf((&xv[r].x)[kk], w0, acc[r]);
    }
  }
#pragma unroll
  for (int r = 0; r < 8; r++) out[(size_t)(row0 + r) * 64 + lane] = acc[r];
}

// ---------------- aggregation (CSR gather, self-loop folded) ----------------

// out[i] = relu( sum_{e: col=i} t[row_e]*dinv[row_e]*dinv[i] + t[i]*dinv[i]^2 + b )
__global__ __launch_bounds__(256) void k_agg128(const float* __restrict__ t, const int* __restrict__ offs,
                                                const int* __restrict__ deg, const int* __restrict__ csr,
                                                const float* __restrict__ dinv, const float* __restrict__ b,
                                                float* __restrict__ out) {
  int wave = threadIdx.x >> 6, lane = threadIdx.x & 63;
  int node = blockIdx.x * 4 + wave;
  if (node >= NN) return;
  float di = dinv[node];
  float2 v = ((const float2*)(t + (size_t)node * 128))[lane];
  float2 acc = make_float2(v.x * di * di, v.y * di * di);
  int beg = offs[node];
  int cnt = deg[node] - 1;
  for (int base = 0; base < cnt; base += 64) {
    int m = min(64, cnt - base);
    int ridx = (lane < m) ? csr[beg + base + lane] : 0;
    float dv = (lane < m) ? dinv[ridx] : 0.f;
    for (int k = 0; k < m; k++) {
      int r = __shfl(ridx, k);
      float s = __shfl(dv, k) * di;
      float2 u = ((const float2*)(t + (size_t)r * 128))[lane];
      acc.x = fmaf(u.x, s, acc.x);
      acc.y = fmaf(u.y, s, acc.y);
    }
  }
  float2 bb = ((const float2*)b)[lane];
  acc.x = fmaxf(acc.x + bb.x, 0.f);
  acc.y = fmaxf(acc.y + bb.y, 0.f);
  ((float2*)(out + (size_t)node * 128))[lane] = acc;
}

// same, 64 features, bias only (no relu) -> final output
__global__ __launch_bounds__(256) void k_agg64(const float* __restrict__ t, const int* __restrict__ offs,
                                               const int* __restrict__ deg, const int* __restrict__ csr,
                                               const float* __restrict__ dinv, const float* __restrict__ b,
                                               float* __restrict__ out) {
  int wave = threadIdx.x >> 6, lane = threadIdx.x & 63;
  int node = blockIdx.x * 4 + wave;
  if (node >= NN) return;
  float di = dinv[node];
  float acc = t[(size_t)node * 64 + lane] * di * di;
  int beg = offs[node];
  int cnt = deg[node] - 1;
  for (int base = 0; base < cnt; base += 64) {
    int m = min(64, cnt - base);
    int ridx = (lane < m) ? csr[beg + base + lane] : 0;
    float dv = (lane < m) ? dinv[ridx] : 0.f;
    for (int k = 0; k < m; k++) {
      int r = __shfl(ridx, k);
      float s = __shfl(dv, k) * di;
      acc = fmaf(t[(size_t)r * 64 + lane], s, acc);
    }
  }
  out[(size_t)node * 64 + lane] = acc + b[lane];
}

// ---------------- host ----------------

extern "C" void kernel_launch(void* const* d_in, const int* in_sizes, int n_in,
                              void* d_out, int out_size, void* d_ws, size_t ws_size,
                              hipStream_t stream) {
  const float* x  = (const float*)d_in[0];
  const int*   ei = (const int*)d_in[1];
  const float* W1 = (const float*)d_in[2];
  const float* b1 = (const float*)d_in[3];
  const float* W2 = (const float*)d_in[4];
  const float* b2 = (const float*)d_in[5];
  float* out = (float*)d_out;

  char* p = (char*)d_ws;
  int* deg    = (int*)p;   p += alignup((size_t)NN * 4);
  int* cursor = (int*)p;   p += alignup((size_t)NN * 4);
  int* offs   = (int*)p;   p += alignup((size_t)NN * 4);
  int* bsums  = (int*)p;   p += alignup(128 * 4);
  float* dinv = (float*)p; p += alignup((size_t)NN * 4);
  int* csr    = (int*)p;   p += alignup((size_t)NE * 4);
  float* t    = (float*)p; p += alignup((size_t)NN * 128 * 4);
  float* h1   = (float*)p; p += alignup((size_t)NN * 128 * 4);
  (void)ws_size; (void)in_sizes; (void)n_in; (void)out_size;

  const int* row = ei;        // edge_index[0]
  const int* col = ei + NE;   // edge_index[1]

  int nbN = (NN + 255) / 256;
  int nbE = (NE + 255) / 256;
  int nbScan = (NN + SCAN_B - 1) / SCAN_B;

  k_init<<<nbN, 256, 0, stream>>>(deg, cursor);
  k_count<<<nbE, 256, 0, stream>>>(col, deg);
  k_dinv<<<nbN, 256, 0, stream>>>(deg, dinv);
  k_scan1<<<nbScan, SCAN_B, 0, stream>>>(deg, offs, bsums);
  k_scan2<<<1, 128, 0, stream>>>(bsums, nbScan);
  k_scan3<<<nbScan, SCAN_B, 0, stream>>>(offs, bsums);
  k_fill<<<nbE, 256, 0, stream>>>(row, col, offs, cursor, csr);

  k_gemm128<<<NN / 16, 256, 0, stream>>>(x, W1, t);
  k_agg128<<<NN / 4, 256, 0, stream>>>(t, offs, deg, csr, dinv, b1, h1);
  k_gemm64<<<NN / 32, 256, 0, stream>>>(h1, W2, t);
  k_agg64<<<NN / 4, 256, 0, stream>>>(t, offs, deg, csr, dinv, b2, out);
}

// Round 2
// 437.724 us; speedup vs baseline: 1.4199x; 1.4199x over previous
//
#include <hip/hip_runtime.h>

#define NN 100000
#define NE 1600000
#define SCAN_B 1024

typedef short bs8 __attribute__((ext_vector_type(8)));
typedef float f32x4 __attribute__((ext_vector_type(4)));
#define MFMA16(a, b, c) __builtin_amdgcn_mfma_f32_16x16x32_bf16(a, b, c, 0, 0, 0)

static inline size_t alignup(size_t x) { return (x + 255) & ~(size_t)255; }

__device__ __forceinline__ ushort f2bf(float f) {  // RNE, finite inputs
  uint u = __float_as_uint(f);
  u += 0x7fffu + ((u >> 16) & 1u);
  return (ushort)(u >> 16);
}
__device__ __forceinline__ float bf2f(ushort s) { return __uint_as_float(((uint)s) << 16); }

// ---------------- graph prep ----------------

__global__ __launch_bounds__(256) void k_init(int* __restrict__ deg, int* __restrict__ cursor) {
  int i = blockIdx.x * 256 + threadIdx.x;
  if (i < NN) { deg[i] = 1; cursor[i] = 0; }  // deg starts at 1 (self loop)
}

__global__ __launch_bounds__(256) void k_count(const int* __restrict__ col, int* __restrict__ deg) {
  int e = blockIdx.x * 256 + threadIdx.x;
  if (e < NE) atomicAdd(&deg[col[e]], 1);
}

__global__ __launch_bounds__(256) void k_dinv(const int* __restrict__ deg, float* __restrict__ dinv) {
  int i = blockIdx.x * 256 + threadIdx.x;
  if (i < NN) dinv[i] = rsqrtf((float)deg[i]);
}

__global__ __launch_bounds__(SCAN_B) void k_scan1(const int* __restrict__ deg, int* __restrict__ offs,
                                                  int* __restrict__ bsums) {
  __shared__ int sm[SCAN_B];
  int i = blockIdx.x * SCAN_B + threadIdx.x;
  int v = (i < NN) ? (deg[i] - 1) : 0;
  sm[threadIdx.x] = v;
  __syncthreads();
  for (int d = 1; d < SCAN_B; d <<= 1) {
    int t = (threadIdx.x >= d) ? sm[threadIdx.x - d] : 0;
    __syncthreads();
    sm[threadIdx.x] += t;
    __syncthreads();
  }
  if (i < NN) offs[i] = sm[threadIdx.x] - v;
  if (threadIdx.x == SCAN_B - 1) bsums[blockIdx.x] = sm[threadIdx.x];
}

__global__ __launch_bounds__(128) void k_scan2(int* __restrict__ bsums, int nb) {
  __shared__ int sm[128];
  int v = (threadIdx.x < nb) ? bsums[threadIdx.x] : 0;
  sm[threadIdx.x] = v;
  __syncthreads();
  for (int d = 1; d < 128; d <<= 1) {
    int t = (threadIdx.x >= d) ? sm[threadIdx.x - d] : 0;
    __syncthreads();
    sm[threadIdx.x] += t;
    __syncthreads();
  }
  if (threadIdx.x < nb) bsums[threadIdx.x] = sm[threadIdx.x] - v;
}

__global__ __launch_bounds__(SCAN_B) void k_scan3(int* __restrict__ offs, const int* __restrict__ bsums) {
  int i = blockIdx.x * SCAN_B + threadIdx.x;
  if (i < NN) offs[i] += bsums[blockIdx.x];
}

__global__ __launch_bounds__(256) void k_fill(const int* __restrict__ row, const int* __restrict__ col,
                                              const int* __restrict__ offs, int* __restrict__ cursor,
                                              int* __restrict__ csr) {
  int e = blockIdx.x * 256 + threadIdx.x;
  if (e < NE) {
    int c = col[e];
    int p = atomicAdd(&cursor[c], 1);
    csr[offs[c] + p] = row[e];
  }
}

// W[K,C] fp32 -> WT[C,K] bf16 (so B-fragments are contiguous 16B loads)
__global__ __launch_bounds__(256) void k_cvtW(const float* __restrict__ W, ushort* __restrict__ WT,
                                              int K, int C) {
  int i = blockIdx.x * 256 + threadIdx.x;
  if (i < K * C) {
    int k = i / C, c = i - k * C;
    WT[c * K + k] = f2bf(W[i]);
  }
}

// ---------------- dense transforms (bf16 MFMA) ----------------

// t[N,128](bf16) = x[N,128](f32) @ W1 ; 4 waves, wave w -> cols [w*32, w*32+32); 64 rows/block
__global__ __launch_bounds__(256) void k_gemm128(const float* __restrict__ x, const ushort* __restrict__ WT,
                                                 ushort* __restrict__ t) {
  int wave = threadIdx.x >> 6, lane = threadIdx.x & 63;
  int col0 = wave * 32;
  int lr = lane & 15;
  int lk = (lane >> 4) * 8;
  bs8 bfrag[2][4];
#pragma unroll
  for (int n = 0; n < 2; n++)
#pragma unroll
    for (int ks = 0; ks < 4; ks++)
      bfrag[n][ks] = *(const bs8*)&WT[(size_t)(col0 + n * 16 + lr) * 128 + ks * 32 + lk];
  int row0 = blockIdx.x * 64;
#pragma unroll 1
  for (int mt = 0; mt < 4; mt++) {
    int r0 = row0 + mt * 16;
    if (r0 >= NN) return;
    const float* xr = x + (size_t)(r0 + lr) * 128 + lk;
    f32x4 acc[2] = {{0.f, 0.f, 0.f, 0.f}, {0.f, 0.f, 0.f, 0.f}};
#pragma unroll
    for (int ks = 0; ks < 4; ks++) {
      float4 a0 = *(const float4*)&xr[ks * 32];
      float4 a1 = *(const float4*)&xr[ks * 32 + 4];
      bs8 af;
      af[0] = (short)f2bf(a0.x); af[1] = (short)f2bf(a0.y);
      af[2] = (short)f2bf(a0.z); af[3] = (short)f2bf(a0.w);
      af[4] = (short)f2bf(a1.x); af[5] = (short)f2bf(a1.y);
      af[6] = (short)f2bf(a1.z); af[7] = (short)f2bf(a1.w);
      acc[0] = MFMA16(af, bfrag[0][ks], acc[0]);
      acc[1] = MFMA16(af, bfrag[1][ks], acc[1]);
    }
    int rbase = r0 + (lane >> 4) * 4;
#pragma unroll
    for (int n = 0; n < 2; n++)
#pragma unroll
      for (int r = 0; r < 4; r++)
        t[(size_t)(rbase + r) * 128 + col0 + n * 16 + lr] = f2bf(acc[n][r]);
  }
}

// t2[N,64](bf16) = h[N,128](bf16) @ W2 ; wave w -> cols [w*16, w*16+16); 64 rows/block
__global__ __launch_bounds__(256) void k_gemm64(const ushort* __restrict__ h, const ushort* __restrict__ WT,
                                                ushort* __restrict__ t2) {
  int wave = threadIdx.x >> 6, lane = threadIdx.x & 63;
  int col0 = wave * 16;
  int lr = lane & 15;
  int lk = (lane >> 4) * 8;
  bs8 bfrag[4];
#pragma unroll
  for (int ks = 0; ks < 4; ks++)
    bfrag[ks] = *(const bs8*)&WT[(size_t)(col0 + lr) * 128 + ks * 32 + lk];
  int row0 = blockIdx.x * 64;
#pragma unroll 1
  for (int mt = 0; mt < 4; mt++) {
    int r0 = row0 + mt * 16;
    if (r0 >= NN) return;
    const ushort* hr = h + (size_t)(r0 + lr) * 128 + lk;
    f32x4 acc = {0.f, 0.f, 0.f, 0.f};
#pragma unroll
    for (int ks = 0; ks < 4; ks++) {
      bs8 af = *(const bs8*)&hr[ks * 32];
      acc = MFMA16(af, bfrag[ks], acc);
    }
    int rbase = r0 + (lane >> 4) * 4;
#pragma unroll
    for (int r = 0; r < 4; r++)
      t2[(size_t)(rbase + r) * 64 + col0 + lr] = f2bf(acc[r]);
  }
}

// ---------------- aggregation (CSR gather, bf16 features, fp32 accum) ----------------

__global__ __launch_bounds__(256) void k_agg128(const ushort* __restrict__ t, const int* __restrict__ offs,
                                                const int* __restrict__ deg, const int* __restrict__ csr,
                                                const float* __restrict__ dinv, const float* __restrict__ b,
                                                ushort* __restrict__ out) {
  int wave = threadIdx.x >> 6, lane = threadIdx.x & 63;
  int node = blockIdx.x * 4 + wave;
  if (node >= NN) return;
  float di = dinv[node];
  uint u = *(const uint*)&t[(size_t)node * 128 + lane * 2];
  float2 acc;
  acc.x = __uint_as_float(u << 16) * di * di;
  acc.y = __uint_as_float(u & 0xffff0000u) * di * di;
  int beg = offs[node];
  int cnt = deg[node] - 1;
  for (int base = 0; base < cnt; base += 64) {
    int m = min(64, cnt - base);
    int ridx = (lane < m) ? csr[beg + base + lane] : 0;
    float dv = (lane < m) ? dinv[ridx] : 0.f;
    for (int k = 0; k < m; k++) {
      int r = __shfl(ridx, k);
      float s = __shfl(dv, k) * di;
      uint uu = *(const uint*)&t[(size_t)r * 128 + lane * 2];
      acc.x = fmaf(__uint_as_float(uu << 16), s, acc.x);
      acc.y = fmaf(__uint_as_float(uu & 0xffff0000u), s, acc.y);
    }
  }
  float2 bb = ((const float2*)b)[lane];
  acc.x = fmaxf(acc.x + bb.x, 0.f);
  acc.y = fmaxf(acc.y + bb.y, 0.f);
  uint packed = (uint)f2bf(acc.x) | ((uint)f2bf(acc.y) << 16);
  *(uint*)&out[(size_t)node * 128 + lane * 2] = packed;
}

__global__ __launch_bounds__(256) void k_agg64(const ushort* __restrict__ t, const int* __restrict__ offs,
                                               const int* __restrict__ deg, const int* __restrict__ csr,
                                               const float* __restrict__ dinv, const float* __restrict__ b,
                                               float* __restrict__ out) {
  int wave = threadIdx.x >> 6, lane = threadIdx.x & 63;
  int node = blockIdx.x * 4 + wave;
  if (node >= NN) return;
  float di = dinv[node];
  float acc = bf2f(t[(size_t)node * 64 + lane]) * di * di;
  int beg = offs[node];
  int cnt = deg[node] - 1;
  for (int base = 0; base < cnt; base += 64) {
    int m = min(64, cnt - base);
    int ridx = (lane < m) ? csr[beg + base + lane] : 0;
    float dv = (lane < m) ? dinv[ridx] : 0.f;
    for (int k = 0; k < m; k++) {
      int r = __shfl(ridx, k);
      float s = __shfl(dv, k) * di;
      acc = fmaf(bf2f(t[(size_t)r * 64 + lane]), s, acc);
    }
  }
  out[(size_t)node * 64 + lane] = acc + b[lane];
}

// ---------------- host ----------------

extern "C" void kernel_launch(void* const* d_in, const int* in_sizes, int n_in,
                              void* d_out, int out_size, void* d_ws, size_t ws_size,
                              hipStream_t stream) {
  const float* x  = (const float*)d_in[0];
  const int*   ei = (const int*)d_in[1];
  const float* W1 = (const float*)d_in[2];
  const float* b1 = (const float*)d_in[3];
  const float* W2 = (const float*)d_in[4];
  const float* b2 = (const float*)d_in[5];
  float* out = (float*)d_out;

  char* p = (char*)d_ws;
  int* deg     = (int*)p;    p += alignup((size_t)NN * 4);
  int* cursor  = (int*)p;    p += alignup((size_t)NN * 4);
  int* offs    = (int*)p;    p += alignup((size_t)NN * 4);
  int* bsums   = (int*)p;    p += alignup(128 * 4);
  float* dinv  = (float*)p;  p += alignup((size_t)NN * 4);
  int* csr     = (int*)p;    p += alignup((size_t)NE * 4);
  ushort* WT1  = (ushort*)p; p += alignup(128 * 128 * 2);
  ushort* WT2  = (ushort*)p; p += alignup(64 * 128 * 2);
  ushort* t    = (ushort*)p; p += alignup((size_t)NN * 128 * 2);  // reused for t2
  ushort* h1   = (ushort*)p; p += alignup((size_t)NN * 128 * 2);
  (void)ws_size; (void)in_sizes; (void)n_in; (void)out_size;

  const int* row = ei;
  const int* col = ei + NE;

  int nbN = (NN + 255) / 256;
  int nbE = (NE + 255) / 256;
  int nbScan = (NN + SCAN_B - 1) / SCAN_B;

  k_init<<<nbN, 256, 0, stream>>>(deg, cursor);
  k_count<<<nbE, 256, 0, stream>>>(col, deg);
  k_dinv<<<nbN, 256, 0, stream>>>(deg, dinv);
  k_scan1<<<nbScan, SCAN_B, 0, stream>>>(deg, offs, bsums);
  k_scan2<<<1, 128, 0, stream>>>(bsums, nbScan);
  k_scan3<<<nbScan, SCAN_B, 0, stream>>>(offs, bsums);
  k_fill<<<nbE, 256, 0, stream>>>(row, col, offs, cursor, csr);
  k_cvtW<<<(128 * 128 + 255) / 256, 256, 0, stream>>>(W1, WT1, 128, 128);
  k_cvtW<<<(128 * 64 + 255) / 256, 256, 0, stream>>>(W2, WT2, 128, 64);

  int nbG = (NN + 63) / 64;
  k_gemm128<<<nbG, 256, 0, stream>>>(x, WT1, t);
  k_agg128<<<NN / 4, 256, 0, stream>>>(t, offs, deg, csr, dinv, b1, h1);
  k_gemm64<<<nbG, 256, 0, stream>>>(h1, WT2, t);
  k_agg64<<<NN / 4, 256, 0, stream>>>(t, offs, deg, csr, dinv, b2, out);
}

// Round 3
// 308.774 us; speedup vs baseline: 2.0129x; 1.4176x over previous
//
#include <hip/hip_runtime.h>

#define NN 100000
#define NE 1600000
#define SCAN_B 1024

// bucketed counting sort params: 512 nodes per bucket
#define BSH 9
#define BSZ 512
#define NBUK 196          // ceil(NN / BSZ)
#define CAP 12288         // per-bucket pair capacity (mean 8163, ~45 sigma margin)
#define CHUNK 4096        // edges per block in k_bucket

typedef short bs8 __attribute__((ext_vector_type(8)));
typedef float f32x4 __attribute__((ext_vector_type(4)));
#define MFMA16(a, b, c) __builtin_amdgcn_mfma_f32_16x16x32_bf16(a, b, c, 0, 0, 0)

static inline size_t alignup(size_t x) { return (x + 255) & ~(size_t)255; }

__device__ __forceinline__ ushort f2bf(float f) {  // RNE, finite inputs
  uint u = __float_as_uint(f);
  u += 0x7fffu + ((u >> 16) & 1u);
  return (ushort)(u >> 16);
}
__device__ __forceinline__ float bf2f(ushort s) { return __uint_as_float(((uint)s) << 16); }

// ---------------- graph prep (bucketed counting sort) ----------------

__global__ __launch_bounds__(256) void k_init(int* __restrict__ gcur) {
  int i = blockIdx.x * 256 + threadIdx.x;
  if (i < NBUK) gcur[i] = i * CAP;
}

// bin edges into buckets: block-level two-phase (LDS hist -> global reserve -> append)
__global__ __launch_bounds__(256) void k_bucket(const int* __restrict__ row, const int* __restrict__ col,
                                                int* __restrict__ gcur, uint2* __restrict__ pairs) {
  __shared__ int cnt[NBUK];
  int t = threadIdx.x;
  for (int i = t; i < NBUK; i += 256) cnt[i] = 0;
  __syncthreads();
  int e0 = blockIdx.x * CHUNK;
  int e1 = min(e0 + CHUNK, NE);
  for (int e = e0 + t; e < e1; e += 256) atomicAdd(&cnt[col[e] >> BSH], 1);
  __syncthreads();
  for (int i = t; i < NBUK; i += 256) {
    int c = cnt[i];
    cnt[i] = c ? atomicAdd(&gcur[i], c) : 0;  // cnt becomes running global cursor
  }
  __syncthreads();
  for (int e = e0 + t; e < e1; e += 256) {
    int c = col[e];
    int p = atomicAdd(&cnt[c >> BSH], 1);
    pairs[p] = make_uint2((uint)row[e], (uint)c);
  }
}

// per-bucket degree count (deg includes +1 self loop)
__global__ __launch_bounds__(256) void k_bdeg(const uint2* __restrict__ pairs, const int* __restrict__ gcur,
                                              int* __restrict__ deg) {
  __shared__ int dc[BSZ];
  int t = threadIdx.x, b = blockIdx.x;
  for (int i = t; i < BSZ; i += 256) dc[i] = 0;
  __syncthreads();
  int s = b * CAP;
  int n = min(gcur[b] - s, CAP);
  for (int i = t; i < n; i += 256) atomicAdd(&dc[pairs[s + i].y & (BSZ - 1)], 1);
  __syncthreads();
  int nb0 = b << BSH;
  for (int i = t; i < BSZ; i += 256) {
    int node = nb0 + i;
    if (node < NN) deg[node] = dc[i] + 1;
  }
}

__global__ __launch_bounds__(256) void k_dinv(const int* __restrict__ deg, float* __restrict__ dinv) {
  int i = blockIdx.x * 256 + threadIdx.x;
  if (i < NN) dinv[i] = rsqrtf((float)deg[i]);
}

__global__ __launch_bounds__(SCAN_B) void k_scan1(const int* __restrict__ deg, int* __restrict__ offs,
                                                  int* __restrict__ bsums) {
  __shared__ int sm[SCAN_B];
  int i = blockIdx.x * SCAN_B + threadIdx.x;
  int v = (i < NN) ? (deg[i] - 1) : 0;
  sm[threadIdx.x] = v;
  __syncthreads();
  for (int d = 1; d < SCAN_B; d <<= 1) {
    int t = (threadIdx.x >= d) ? sm[threadIdx.x - d] : 0;
    __syncthreads();
    sm[threadIdx.x] += t;
    __syncthreads();
  }
  if (i < NN) offs[i] = sm[threadIdx.x] - v;
  if (threadIdx.x == SCAN_B - 1) bsums[blockIdx.x] = sm[threadIdx.x];
}

__global__ __launch_bounds__(128) void k_scan2(int* __restrict__ bsums, int nb) {
  __shared__ int sm[128];
  int v = (threadIdx.x < nb) ? bsums[threadIdx.x] : 0;
  sm[threadIdx.x] = v;
  __syncthreads();
  for (int d = 1; d < 128; d <<= 1) {
    int t = (threadIdx.x >= d) ? sm[threadIdx.x - d] : 0;
    __syncthreads();
    sm[threadIdx.x] += t;
    __syncthreads();
  }
  if (threadIdx.x < nb) bsums[threadIdx.x] = sm[threadIdx.x] - v;
}

__global__ __launch_bounds__(SCAN_B) void k_scan3(int* __restrict__ offs, const int* __restrict__ bsums) {
  int i = blockIdx.x * SCAN_B + threadIdx.x;
  if (i < NN) offs[i] += bsums[blockIdx.x];
}

// per-bucket CSR fill: offs preloaded to LDS, writes land in ~32KB L2-resident window
__global__ __launch_bounds__(256) void k_bfill(const uint2* __restrict__ pairs, const int* __restrict__ gcur,
                                               const int* __restrict__ offs, int* __restrict__ csr) {
  __shared__ int loff[BSZ];
  __shared__ int cur[BSZ];
  int t = threadIdx.x, b = blockIdx.x;
  int nb0 = b << BSH;
  for (int i = t; i < BSZ; i += 256) {
    int node = nb0 + i;
    loff[i] = (node < NN) ? offs[node] : 0;
    cur[i] = 0;
  }
  __syncthreads();
  int s = b * CAP;
  int n = min(gcur[b] - s, CAP);
  for (int i = t; i < n; i += 256) {
    uint2 pr = pairs[s + i];
    int li = pr.y & (BSZ - 1);
    int p = atomicAdd(&cur[li], 1);
    csr[loff[li] + p] = (int)pr.x;
  }
}

// W[K,C] fp32 -> WT[C,K] bf16
__global__ __launch_bounds__(256) void k_cvtW(const float* __restrict__ W, ushort* __restrict__ WT,
                                              int K, int C) {
  int i = blockIdx.x * 256 + threadIdx.x;
  if (i < K * C) {
    int k = i / C, c = i - k * C;
    WT[c * K + k] = f2bf(W[i]);
  }
}

// ---------------- dense transforms (bf16 MFMA) ----------------

__global__ __launch_bounds__(256) void k_gemm128(const float* __restrict__ x, const ushort* __restrict__ WT,
                                                 ushort* __restrict__ t) {
  int wave = threadIdx.x >> 6, lane = threadIdx.x & 63;
  int col0 = wave * 32;
  int lr = lane & 15;
  int lk = (lane >> 4) * 8;
  bs8 bfrag[2][4];
#pragma unroll
  for (int n = 0; n < 2; n++)
#pragma unroll
    for (int ks = 0; ks < 4; ks++)
      bfrag[n][ks] = *(const bs8*)&WT[(size_t)(col0 + n * 16 + lr) * 128 + ks * 32 + lk];
  int row0 = blockIdx.x * 64;
#pragma unroll 1
  for (int mt = 0; mt < 4; mt++) {
    int r0 = row0 + mt * 16;
    if (r0 >= NN) return;
    const float* xr = x + (size_t)(r0 + lr) * 128 + lk;
    f32x4 acc[2] = {{0.f, 0.f, 0.f, 0.f}, {0.f, 0.f, 0.f, 0.f}};
#pragma unroll
    for (int ks = 0; ks < 4; ks++) {
      float4 a0 = *(const float4*)&xr[ks * 32];
      float4 a1 = *(const float4*)&xr[ks * 32 + 4];
      bs8 af;
      af[0] = (short)f2bf(a0.x); af[1] = (short)f2bf(a0.y);
      af[2] = (short)f2bf(a0.z); af[3] = (short)f2bf(a0.w);
      af[4] = (short)f2bf(a1.x); af[5] = (short)f2bf(a1.y);
      af[6] = (short)f2bf(a1.z); af[7] = (short)f2bf(a1.w);
      acc[0] = MFMA16(af, bfrag[0][ks], acc[0]);
      acc[1] = MFMA16(af, bfrag[1][ks], acc[1]);
    }
    int rbase = r0 + (lane >> 4) * 4;
#pragma unroll
    for (int n = 0; n < 2; n++)
#pragma unroll
      for (int r = 0; r < 4; r++)
        t[(size_t)(rbase + r) * 128 + col0 + n * 16 + lr] = f2bf(acc[n][r]);
  }
}

__global__ __launch_bounds__(256) void k_gemm64(const ushort* __restrict__ h, const ushort* __restrict__ WT,
                                                ushort* __restrict__ t2) {
  int wave = threadIdx.x >> 6, lane = threadIdx.x & 63;
  int col0 = wave * 16;
  int lr = lane & 15;
  int lk = (lane >> 4) * 8;
  bs8 bfrag[4];
#pragma unroll
  for (int ks = 0; ks < 4; ks++)
    bfrag[ks] = *(const bs8*)&WT[(size_t)(col0 + lr) * 128 + ks * 32 + lk];
  int row0 = blockIdx.x * 64;
#pragma unroll 1
  for (int mt = 0; mt < 4; mt++) {
    int r0 = row0 + mt * 16;
    if (r0 >= NN) return;
    const ushort* hr = h + (size_t)(r0 + lr) * 128 + lk;
    f32x4 acc = {0.f, 0.f, 0.f, 0.f};
#pragma unroll
    for (int ks = 0; ks < 4; ks++) {
      bs8 af = *(const bs8*)&hr[ks * 32];
      acc = MFMA16(af, bfrag[ks], acc);
    }
    int rbase = r0 + (lane >> 4) * 4;
#pragma unroll
    for (int r = 0; r < 4; r++)
      t2[(size_t)(rbase + r) * 64 + col0 + lr] = f2bf(acc[r]);
  }
}

// ---------------- aggregation (CSR gather, bf16 features, fp32 accum) ----------------

__global__ __launch_bounds__(256) void k_agg128(const ushort* __restrict__ t, const int* __restrict__ offs,
                                                const int* __restrict__ deg, const int* __restrict__ csr,
                                                const float* __restrict__ dinv, const float* __restrict__ b,
                                                ushort* __restrict__ out) {
  int wave = threadIdx.x >> 6, lane = threadIdx.x & 63;
  int node = blockIdx.x * 4 + wave;
  if (node >= NN) return;
  float di = dinv[node];
  uint u = *(const uint*)&t[(size_t)node * 128 + lane * 2];
  float2 acc;
  acc.x = __uint_as_float(u << 16) * di * di;
  acc.y = __uint_as_float(u & 0xffff0000u) * di * di;
  int beg = offs[node];
  int cnt = deg[node] - 1;
  for (int base = 0; base < cnt; base += 64) {
    int m = min(64, cnt - base);
    int ridx = (lane < m) ? csr[beg + base + lane] : 0;
    float dv = (lane < m) ? dinv[ridx] : 0.f;
    for (int k = 0; k < m; k++) {
      int r = __shfl(ridx, k);
      float s = __shfl(dv, k) * di;
      uint uu = *(const uint*)&t[(size_t)r * 128 + lane * 2];
      acc.x = fmaf(__uint_as_float(uu << 16), s, acc.x);
      acc.y = fmaf(__uint_as_float(uu & 0xffff0000u), s, acc.y);
    }
  }
  float2 bb = ((const float2*)b)[lane];
  acc.x = fmaxf(acc.x + bb.x, 0.f);
  acc.y = fmaxf(acc.y + bb.y, 0.f);
  uint packed = (uint)f2bf(acc.x) | ((uint)f2bf(acc.y) << 16);
  *(uint*)&out[(size_t)node * 128 + lane * 2] = packed;
}

// half-wave: lanes 0-31 edge A, lanes 32-63 edge B; 4B/lane loads; combine via shfl_xor(32)
__global__ __launch_bounds__(256) void k_agg64(const ushort* __restrict__ t, const int* __restrict__ offs,
                                               const int* __restrict__ deg, const int* __restrict__ csr,
                                               const float* __restrict__ dinv, const float* __restrict__ b,
                                               float* __restrict__ out) {
  int wave = threadIdx.x >> 6, lane = threadIdx.x & 63;
  int node = blockIdx.x * 4 + wave;
  if (node >= NN) return;
  int half = lane >> 5, fl = lane & 31;
  float di = dinv[node];
  float2 acc = make_float2(0.f, 0.f);
  if (half == 0) {
    uint u = *(const uint*)&t[(size_t)node * 64 + fl * 2];
    acc.x = __uint_as_float(u << 16) * di * di;
    acc.y = __uint_as_float(u & 0xffff0000u) * di * di;
  }
  int beg = offs[node];
  int cnt = deg[node] - 1;
  for (int base = 0; base < cnt; base += 64) {
    int m = min(64, cnt - base);
    int ridx = (lane < m) ? csr[beg + base + lane] : 0;
    float dv = (lane < m) ? dinv[ridx] : 0.f;
    int iter = (m + 1) >> 1;
    for (int k = 0; k < iter; k++) {
      int ei = 2 * k + half;
      int r = __shfl(ridx, ei);
      float s = __shfl(dv, ei) * di;  // s==0 masks ei>=m (and tail edge for half 1)
      uint uu = *(const uint*)&t[(size_t)r * 64 + fl * 2];
      acc.x = fmaf(__uint_as_float(uu << 16), s, acc.x);
      acc.y = fmaf(__uint_as_float(uu & 0xffff0000u), s, acc.y);
    }
  }
  acc.x += __shfl_xor(acc.x, 32);
  acc.y += __shfl_xor(acc.y, 32);
  if (half == 0) {
    float2 bb = ((const float2*)b)[fl];
    ((float2*)(out + (size_t)node * 64))[fl] = make_float2(acc.x + bb.x, acc.y + bb.y);
  }
}

// ---------------- host ----------------

extern "C" void kernel_launch(void* const* d_in, const int* in_sizes, int n_in,
                              void* d_out, int out_size, void* d_ws, size_t ws_size,
                              hipStream_t stream) {
  const float* x  = (const float*)d_in[0];
  const int*   ei = (const int*)d_in[1];
  const float* W1 = (const float*)d_in[2];
  const float* b1 = (const float*)d_in[3];
  const float* W2 = (const float*)d_in[4];
  const float* b2 = (const float*)d_in[5];
  float* out = (float*)d_out;

  char* p = (char*)d_ws;
  int* deg     = (int*)p;    p += alignup((size_t)NN * 4);
  int* gcur    = (int*)p;    p += alignup((size_t)NBUK * 4);
  int* offs    = (int*)p;    p += alignup((size_t)NN * 4);
  int* bsums   = (int*)p;    p += alignup(128 * 4);
  float* dinv  = (float*)p;  p += alignup((size_t)NN * 4);
  int* csr     = (int*)p;    p += alignup((size_t)NE * 4);
  ushort* WT1  = (ushort*)p; p += alignup(128 * 128 * 2);
  ushort* WT2  = (ushort*)p; p += alignup(64 * 128 * 2);
  ushort* t    = (ushort*)p; p += alignup((size_t)NN * 128 * 2);  // reused for t2
  ushort* h1   = (ushort*)p; p += alignup((size_t)NN * 128 * 2);
  uint2* pairs = (uint2*)p;  p += alignup((size_t)NBUK * CAP * 8);
  (void)ws_size; (void)in_sizes; (void)n_in; (void)out_size;

  const int* row = ei;
  const int* col = ei + NE;

  int nbScan = (NN + SCAN_B - 1) / SCAN_B;
  int nbB = (NE + CHUNK - 1) / CHUNK;

  k_init<<<1, 256, 0, stream>>>(gcur);
  k_bucket<<<nbB, 256, 0, stream>>>(row, col, gcur, pairs);
  k_bdeg<<<NBUK, 256, 0, stream>>>(pairs, gcur, deg);
  k_dinv<<<(NN + 255) / 256, 256, 0, stream>>>(deg, dinv);
  k_scan1<<<nbScan, SCAN_B, 0, stream>>>(deg, offs, bsums);
  k_scan2<<<1, 128, 0, stream>>>(bsums, nbScan);
  k_scan3<<<nbScan, SCAN_B, 0, stream>>>(offs, bsums);
  k_bfill<<<NBUK, 256, 0, stream>>>(pairs, gcur, offs, csr);
  k_cvtW<<<(128 * 128 + 255) / 256, 256, 0, stream>>>(W1, WT1, 128, 128);
  k_cvtW<<<(128 * 64 + 255) / 256, 256, 0, stream>>>(W2, WT2, 128, 64);

  int nbG = (NN + 63) / 64;
  k_gemm128<<<nbG, 256, 0, stream>>>(x, WT1, t);
  k_agg128<<<NN / 4, 256, 0, stream>>>(t, offs, deg, csr, dinv, b1, h1);
  k_gemm64<<<nbG, 256, 0, stream>>>(h1, WT2, t);
  k_agg64<<<NN / 4, 256, 0, stream>>>(t, offs, deg, csr, dinv, b2, out);
}

// Round 4
// 251.079 us; speedup vs baseline: 2.4754x; 1.2298x over previous
//
#include <hip/hip_runtime.h>

#define NN 100000
#define NE 1600000
#define SCAN_B 1024

// bucketed counting sort params: 512 nodes per bucket
#define BSH 9
#define BSZ 512
#define NBUK 196          // ceil(NN / BSZ)
#define CAP 12288         // per-bucket pair capacity (mean 8163, huge margin)
#define CHUNK 4096        // edges per block in k_bucket

typedef short bs8 __attribute__((ext_vector_type(8)));
typedef float f32x4 __attribute__((ext_vector_type(4)));
#define MFMA16(a, b, c) __builtin_amdgcn_mfma_f32_16x16x32_bf16(a, b, c, 0, 0, 0)

static inline size_t alignup(size_t x) { return (x + 255) & ~(size_t)255; }

__device__ __forceinline__ ushort f2bf(float f) {  // RNE, finite inputs
  uint u = __float_as_uint(f);
  u += 0x7fffu + ((u >> 16) & 1u);
  return (ushort)(u >> 16);
}
__device__ __forceinline__ float bf2f(ushort s) { return __uint_as_float(((uint)s) << 16); }
__device__ __forceinline__ float bflo(uint u) { return __uint_as_float(u << 16); }
__device__ __forceinline__ float bfhi(uint u) { return __uint_as_float(u & 0xffff0000u); }

// ---------------- graph prep (bucketed counting sort) ----------------

__global__ __launch_bounds__(256) void k_init(int* __restrict__ gcur) {
  int i = blockIdx.x * 256 + threadIdx.x;
  if (i < NBUK) gcur[i] = i * CAP;
}

// bin edges into buckets: block-level two-phase (LDS hist -> global reserve -> append)
__global__ __launch_bounds__(256) void k_bucket(const int* __restrict__ row, const int* __restrict__ col,
                                                int* __restrict__ gcur, uint* __restrict__ pr_row,
                                                ushort* __restrict__ pr_li) {
  __shared__ int cnt[NBUK];
  int t = threadIdx.x;
  for (int i = t; i < NBUK; i += 256) cnt[i] = 0;
  __syncthreads();
  int e0 = blockIdx.x * CHUNK;
  int e1 = min(e0 + CHUNK, NE);
  for (int e = e0 + t; e < e1; e += 256) atomicAdd(&cnt[col[e] >> BSH], 1);
  __syncthreads();
  for (int i = t; i < NBUK; i += 256) {
    int c = cnt[i];
    cnt[i] = c ? atomicAdd(&gcur[i], c) : 0;  // cnt becomes running global cursor
  }
  __syncthreads();
  for (int e = e0 + t; e < e1; e += 256) {
    int c = col[e];
    int p = atomicAdd(&cnt[c >> BSH], 1);
    pr_row[p] = (uint)row[e];
    pr_li[p] = (ushort)(c & (BSZ - 1));
  }
}

// per-bucket degree count (deg includes +1 self loop)
__global__ __launch_bounds__(256) void k_bdeg(const ushort* __restrict__ pr_li, const int* __restrict__ gcur,
                                              int* __restrict__ deg) {
  __shared__ int dc[BSZ];
  int t = threadIdx.x, b = blockIdx.x;
  for (int i = t; i < BSZ; i += 256) dc[i] = 0;
  __syncthreads();
  int s = b * CAP;
  int n = min(gcur[b] - s, CAP);
  for (int i = t; i < n; i += 256) atomicAdd(&dc[pr_li[s + i]], 1);
  __syncthreads();
  int nb0 = b << BSH;
  for (int i = t; i < BSZ; i += 256) {
    int node = nb0 + i;
    if (node < NN) deg[node] = dc[i] + 1;
  }
}

__global__ __launch_bounds__(256) void k_dinv(const int* __restrict__ deg, float* __restrict__ dinv) {
  int i = blockIdx.x * 256 + threadIdx.x;
  if (i < NN) dinv[i] = rsqrtf((float)deg[i]);
}

__global__ __launch_bounds__(SCAN_B) void k_scan1(const int* __restrict__ deg, int* __restrict__ offs,
                                                  int* __restrict__ bsums) {
  __shared__ int sm[SCAN_B];
  int i = blockIdx.x * SCAN_B + threadIdx.x;
  int v = (i < NN) ? (deg[i] - 1) : 0;
  sm[threadIdx.x] = v;
  __syncthreads();
  for (int d = 1; d < SCAN_B; d <<= 1) {
    int t = (threadIdx.x >= d) ? sm[threadIdx.x - d] : 0;
    __syncthreads();
    sm[threadIdx.x] += t;
    __syncthreads();
  }
  if (i < NN) offs[i] = sm[threadIdx.x] - v;
  if (threadIdx.x == SCAN_B - 1) bsums[blockIdx.x] = sm[threadIdx.x];
}

__global__ __launch_bounds__(128) void k_scan2(int* __restrict__ bsums, int nb) {
  __shared__ int sm[128];
  int v = (threadIdx.x < nb) ? bsums[threadIdx.x] : 0;
  sm[threadIdx.x] = v;
  __syncthreads();
  for (int d = 1; d < 128; d <<= 1) {
    int t = (threadIdx.x >= d) ? sm[threadIdx.x - d] : 0;
    __syncthreads();
    sm[threadIdx.x] += t;
    __syncthreads();
  }
  if (threadIdx.x < nb) bsums[threadIdx.x] = sm[threadIdx.x] - v;
}

__global__ __launch_bounds__(SCAN_B) void k_scan3(int* __restrict__ offs, const int* __restrict__ bsums) {
  int i = blockIdx.x * SCAN_B + threadIdx.x;
  if (i < NN) offs[i] += bsums[blockIdx.x];
}

// per-bucket weighted-CSR fill: wcsr[e] = (row, dinv[row]*dinv[col])
__global__ __launch_bounds__(256) void k_bfill(const uint* __restrict__ pr_row, const ushort* __restrict__ pr_li,
                                               const int* __restrict__ gcur, const int* __restrict__ offs,
                                               const float* __restrict__ dinv, uint2* __restrict__ wcsr) {
  __shared__ int loff[BSZ];
  __shared__ int cur[BSZ];
  __shared__ float dl[BSZ];
  int t = threadIdx.x, b = blockIdx.x;
  int nb0 = b << BSH;
  for (int i = t; i < BSZ; i += 256) {
    int node = nb0 + i;
    loff[i] = (node < NN) ? offs[node] : 0;
    dl[i] = (node < NN) ? dinv[node] : 0.f;
    cur[i] = 0;
  }
  __syncthreads();
  int s = b * CAP;
  int n = min(gcur[b] - s, CAP);
  for (int i = t; i < n; i += 256) {
    int li = pr_li[s + i];
    uint r = pr_row[s + i];
    int p = atomicAdd(&cur[li], 1);
    wcsr[loff[li] + p] = make_uint2(r, __float_as_uint(dinv[r] * dl[li]));
  }
}

// W[K,C] fp32 -> WT[C,K] bf16
__global__ __launch_bounds__(256) void k_cvtW(const float* __restrict__ W, ushort* __restrict__ WT,
                                              int K, int C) {
  int i = blockIdx.x * 256 + threadIdx.x;
  if (i < K * C) {
    int k = i / C, c = i - k * C;
    WT[c * K + k] = f2bf(W[i]);
  }
}

// ---------------- dense transforms (bf16 MFMA) ----------------

__global__ __launch_bounds__(256) void k_gemm128(const float* __restrict__ x, const ushort* __restrict__ WT,
                                                 ushort* __restrict__ t) {
  int wave = threadIdx.x >> 6, lane = threadIdx.x & 63;
  int col0 = wave * 32;
  int lr = lane & 15;
  int lk = (lane >> 4) * 8;
  bs8 bfrag[2][4];
#pragma unroll
  for (int n = 0; n < 2; n++)
#pragma unroll
    for (int ks = 0; ks < 4; ks++)
      bfrag[n][ks] = *(const bs8*)&WT[(size_t)(col0 + n * 16 + lr) * 128 + ks * 32 + lk];
  int row0 = blockIdx.x * 64;
#pragma unroll 1
  for (int mt = 0; mt < 4; mt++) {
    int r0 = row0 + mt * 16;
    if (r0 >= NN) return;
    const float* xr = x + (size_t)(r0 + lr) * 128 + lk;
    f32x4 acc[2] = {{0.f, 0.f, 0.f, 0.f}, {0.f, 0.f, 0.f, 0.f}};
#pragma unroll
    for (int ks = 0; ks < 4; ks++) {
      float4 a0 = *(const float4*)&xr[ks * 32];
      float4 a1 = *(const float4*)&xr[ks * 32 + 4];
      bs8 af;
      af[0] = (short)f2bf(a0.x); af[1] = (short)f2bf(a0.y);
      af[2] = (short)f2bf(a0.z); af[3] = (short)f2bf(a0.w);
      af[4] = (short)f2bf(a1.x); af[5] = (short)f2bf(a1.y);
      af[6] = (short)f2bf(a1.z); af[7] = (short)f2bf(a1.w);
      acc[0] = MFMA16(af, bfrag[0][ks], acc[0]);
      acc[1] = MFMA16(af, bfrag[1][ks], acc[1]);
    }
    int rbase = r0 + (lane >> 4) * 4;
#pragma unroll
    for (int n = 0; n < 2; n++)
#pragma unroll
      for (int r = 0; r < 4; r++)
        t[(size_t)(rbase + r) * 128 + col0 + n * 16 + lr] = f2bf(acc[n][r]);
  }
}

__global__ __launch_bounds__(256) void k_gemm64(const ushort* __restrict__ h, const ushort* __restrict__ WT,
                                                ushort* __restrict__ t2) {
  int wave = threadIdx.x >> 6, lane = threadIdx.x & 63;
  int col0 = wave * 16;
  int lr = lane & 15;
  int lk = (lane >> 4) * 8;
  bs8 bfrag[4];
#pragma unroll
  for (int ks = 0; ks < 4; ks++)
    bfrag[ks] = *(const bs8*)&WT[(size_t)(col0 + lr) * 128 + ks * 32 + lk];
  int row0 = blockIdx.x * 64;
#pragma unroll 1
  for (int mt = 0; mt < 4; mt++) {
    int r0 = row0 + mt * 16;
    if (r0 >= NN) return;
    const ushort* hr = h + (size_t)(r0 + lr) * 128 + lk;
    f32x4 acc = {0.f, 0.f, 0.f, 0.f};
#pragma unroll
    for (int ks = 0; ks < 4; ks++) {
      bs8 af = *(const bs8*)&hr[ks * 32];
      acc = MFMA16(af, bfrag[ks], acc);
    }
    int rbase = r0 + (lane >> 4) * 4;
#pragma unroll
    for (int r = 0; r < 4; r++)
      t2[(size_t)(rbase + r) * 64 + col0 + lr] = f2bf(acc[r]);
  }
}

// ---------------- aggregation (grouped-lane wide gathers, fp32 accum) ----------------

// 4 groups of 16 lanes; group g handles edge 4k+g; lane loads 16B (8 bf16 feats)
__global__ __launch_bounds__(256) void k_agg128(const ushort* __restrict__ t, const int* __restrict__ offs,
                                                const int* __restrict__ deg, const uint2* __restrict__ wcsr,
                                                const float* __restrict__ dinv, const float* __restrict__ b,
                                                ushort* __restrict__ out) {
  int wave = threadIdx.x >> 6, lane = threadIdx.x & 63;
  int node = blockIdx.x * 4 + wave;
  if (node >= NN) return;
  int g = lane >> 4, fl = lane & 15;
  float acc[8] = {};
  int beg = offs[node];
  int cnt = deg[node] - 1;
  const char* tb = (const char*)t;
  for (int base = 0; base < cnt; base += 64) {
    int m = min(64, cnt - base);
    uint2 pr = (lane < m) ? wcsr[beg + base + lane] : make_uint2(0u, 0u);
    int ridx = (int)pr.x;
    float nrm = __uint_as_float(pr.y);
    int mm = (m + 3) >> 2;
    for (int k = 0; k < mm; k++) {
      int src = k * 4 + g;
      int r = __shfl(ridx, src);
      float s = __shfl(nrm, src);  // 0 for padded slots
      uint4 uu = *(const uint4*)(tb + (((uint)r << 8) + (fl << 4)));
      acc[0] = fmaf(bflo(uu.x), s, acc[0]);
      acc[1] = fmaf(bfhi(uu.x), s, acc[1]);
      acc[2] = fmaf(bflo(uu.y), s, acc[2]);
      acc[3] = fmaf(bfhi(uu.y), s, acc[3]);
      acc[4] = fmaf(bflo(uu.z), s, acc[4]);
      acc[5] = fmaf(bfhi(uu.z), s, acc[5]);
      acc[6] = fmaf(bflo(uu.w), s, acc[6]);
      acc[7] = fmaf(bfhi(uu.w), s, acc[7]);
    }
  }
#pragma unroll
  for (int j = 0; j < 8; j++) {
    acc[j] += __shfl_xor(acc[j], 16);
    acc[j] += __shfl_xor(acc[j], 32);
  }
  if (g == 0) {
    float di = dinv[node];
    float d2 = di * di;
    uint4 sv = *(const uint4*)(tb + (((uint)node << 8) + (fl << 4)));
    float4 b0 = *(const float4*)&b[fl * 8];
    float4 b1 = *(const float4*)&b[fl * 8 + 4];
    float o0 = fmaxf(fmaf(bflo(sv.x), d2, acc[0]) + b0.x, 0.f);
    float o1 = fmaxf(fmaf(bfhi(sv.x), d2, acc[1]) + b0.y, 0.f);
    float o2 = fmaxf(fmaf(bflo(sv.y), d2, acc[2]) + b0.z, 0.f);
    float o3 = fmaxf(fmaf(bfhi(sv.y), d2, acc[3]) + b0.w, 0.f);
    float o4 = fmaxf(fmaf(bflo(sv.z), d2, acc[4]) + b1.x, 0.f);
    float o5 = fmaxf(fmaf(bfhi(sv.z), d2, acc[5]) + b1.y, 0.f);
    float o6 = fmaxf(fmaf(bflo(sv.w), d2, acc[6]) + b1.z, 0.f);
    float o7 = fmaxf(fmaf(bfhi(sv.w), d2, acc[7]) + b1.w, 0.f);
    uint4 pk;
    pk.x = (uint)f2bf(o0) | ((uint)f2bf(o1) << 16);
    pk.y = (uint)f2bf(o2) | ((uint)f2bf(o3) << 16);
    pk.z = (uint)f2bf(o4) | ((uint)f2bf(o5) << 16);
    pk.w = (uint)f2bf(o6) | ((uint)f2bf(o7) << 16);
    *(uint4*)&out[(size_t)node * 128 + fl * 8] = pk;
  }
}

// 8 groups of 8 lanes; group g handles edge 8k+g; lane loads 16B (8 bf16 feats)
__global__ __launch_bounds__(256) void k_agg64(const ushort* __restrict__ t, const int* __restrict__ offs,
                                               const int* __restrict__ deg, const uint2* __restrict__ wcsr,
                                               const float* __restrict__ dinv, const float* __restrict__ b,
                                               float* __restrict__ out) {
  int wave = threadIdx.x >> 6, lane = threadIdx.x & 63;
  int node = blockIdx.x * 4 + wave;
  if (node >= NN) return;
  int g = lane >> 3, fl = lane & 7;
  float acc[8] = {};
  int beg = offs[node];
  int cnt = deg[node] - 1;
  const char* tb = (const char*)t;
  for (int base = 0; base < cnt; base += 64) {
    int m = min(64, cnt - base);
    uint2 pr = (lane < m) ? wcsr[beg + base + lane] : make_uint2(0u, 0u);
    int ridx = (int)pr.x;
    float nrm = __uint_as_float(pr.y);
    int mm = (m + 7) >> 3;
    for (int k = 0; k < mm; k++) {
      int src = k * 8 + g;
      int r = __shfl(ridx, src);
      float s = __shfl(nrm, src);
      uint4 uu = *(const uint4*)(tb + (((uint)r << 7) + (fl << 4)));
      acc[0] = fmaf(bflo(uu.x), s, acc[0]);
      acc[1] = fmaf(bfhi(uu.x), s, acc[1]);
      acc[2] = fmaf(bflo(uu.y), s, acc[2]);
      acc[3] = fmaf(bfhi(uu.y), s, acc[3]);
      acc[4] = fmaf(bflo(uu.z), s, acc[4]);
      acc[5] = fmaf(bfhi(uu.z), s, acc[5]);
      acc[6] = fmaf(bflo(uu.w), s, acc[6]);
      acc[7] = fmaf(bfhi(uu.w), s, acc[7]);
    }
  }
#pragma unroll
  for (int j = 0; j < 8; j++) {
    acc[j] += __shfl_xor(acc[j], 8);
    acc[j] += __shfl_xor(acc[j], 16);
    acc[j] += __shfl_xor(acc[j], 32);
  }
  if (g == 0) {
    float di = dinv[node];
    float d2 = di * di;
    uint4 sv = *(const uint4*)(tb + (((uint)node << 7) + (fl << 4)));
    float4 b0 = *(const float4*)&b[fl * 8];
    float4 b1 = *(const float4*)&b[fl * 8 + 4];
    float4 o0, o1;
    o0.x = fmaf(bflo(sv.x), d2, acc[0]) + b0.x;
    o0.y = fmaf(bfhi(sv.x), d2, acc[1]) + b0.y;
    o0.z = fmaf(bflo(sv.y), d2, acc[2]) + b0.z;
    o0.w = fmaf(bfhi(sv.y), d2, acc[3]) + b0.w;
    o1.x = fmaf(bflo(sv.z), d2, acc[4]) + b1.x;
    o1.y = fmaf(bfhi(sv.z), d2, acc[5]) + b1.y;
    o1.z = fmaf(bflo(sv.w), d2, acc[6]) + b1.z;
    o1.w = fmaf(bfhi(sv.w), d2, acc[7]) + b1.w;
    *(float4*)&out[(size_t)node * 64 + fl * 8] = o0;
    *(float4*)&out[(size_t)node * 64 + fl * 8 + 4] = o1;
  }
}

// ---------------- host ----------------

extern "C" void kernel_launch(void* const* d_in, const int* in_sizes, int n_in,
                              void* d_out, int out_size, void* d_ws, size_t ws_size,
                              hipStream_t stream) {
  const float* x  = (const float*)d_in[0];
  const int*   ei = (const int*)d_in[1];
  const float* W1 = (const float*)d_in[2];
  const float* b1 = (const float*)d_in[3];
  const float* W2 = (const float*)d_in[4];
  const float* b2 = (const float*)d_in[5];
  float* out = (float*)d_out;

  char* p = (char*)d_ws;
  int* deg      = (int*)p;    p += alignup((size_t)NN * 4);
  int* gcur     = (int*)p;    p += alignup((size_t)NBUK * 4);
  int* offs     = (int*)p;    p += alignup((size_t)NN * 4);
  int* bsums    = (int*)p;    p += alignup(128 * 4);
  float* dinv   = (float*)p;  p += alignup((size_t)NN * 4);
  uint2* wcsr   = (uint2*)p;  p += alignup((size_t)NE * 8);
  ushort* WT1   = (ushort*)p; p += alignup(128 * 128 * 2);
  ushort* WT2   = (ushort*)p; p += alignup(64 * 128 * 2);
  ushort* t     = (ushort*)p; p += alignup((size_t)NN * 128 * 2);  // reused for t2
  ushort* h1    = (ushort*)p; p += alignup((size_t)NN * 128 * 2);
  uint* pr_row  = (uint*)p;   p += alignup((size_t)NBUK * CAP * 4);
  ushort* pr_li = (ushort*)p; p += alignup((size_t)NBUK * CAP * 2);
  (void)ws_size; (void)in_sizes; (void)n_in; (void)out_size;

  const int* row = ei;
  const int* col = ei + NE;

  int nbScan = (NN + SCAN_B - 1) / SCAN_B;
  int nbB = (NE + CHUNK - 1) / CHUNK;

  k_init<<<1, 256, 0, stream>>>(gcur);
  k_bucket<<<nbB, 256, 0, stream>>>(row, col, gcur, pr_row, pr_li);
  k_bdeg<<<NBUK, 256, 0, stream>>>(pr_li, gcur, deg);
  k_dinv<<<(NN + 255) / 256, 256, 0, stream>>>(deg, dinv);
  k_scan1<<<nbScan, SCAN_B, 0, stream>>>(deg, offs, bsums);
  k_scan2<<<1, 128, 0, stream>>>(bsums, nbScan);
  k_scan3<<<nbScan, SCAN_B, 0, stream>>>(offs, bsums);
  k_bfill<<<NBUK, 256, 0, stream>>>(pr_row, pr_li, gcur, offs, dinv, wcsr);
  k_cvtW<<<(128 * 128 + 255) / 256, 256, 0, stream>>>(W1, WT1, 128, 128);
  k_cvtW<<<(128 * 64 + 255) / 256, 256, 0, stream>>>(W2, WT2, 128, 64);

  int nbG = (NN + 63) / 64;
  k_gemm128<<<nbG, 256, 0, stream>>>(x, WT1, t);
  k_agg128<<<NN / 4, 256, 0, stream>>>(t, offs, deg, wcsr, dinv, b1, h1);
  k_gemm64<<<nbG, 256, 0, stream>>>(h1, WT2, t);
  k_agg64<<<NN / 4, 256, 0, stream>>>(t, offs, deg, wcsr, dinv, b2, out);
}